// Round 4
// baseline (101.840 us; speedup 1.0000x reference)
//
#include <hip/hip_runtime.h>

typedef _Float16 half8 __attribute__((ext_vector_type(8)));
typedef float floatx4 __attribute__((ext_vector_type(4)));
typedef float floatx2 __attribute__((ext_vector_type(2)));

#define BB 8
#define NN 64
#define DD 64
#define EE 32

__device__ __forceinline__ float sigmoidf_(float x) { return 1.f / (1.f + __expf(-x)); }
__device__ __forceinline__ float tanhf_(float x) {
    float e = __expf(2.f * x);
    return (e - 1.f) / (e + 1.f);
}
__device__ __forceinline__ floatx2 relu2(floatx2 v) {
    floatx2 z = {0.f, 0.f};
    return __builtin_elementwise_max(v, z);
}

// Single fused kernel. One block per (b, i_node) = one output row; 512 blocks,
// all co-resident (launch_bounds(256,2) => >=2 blocks/CU; grid == 256*2).
//
// Phase P (blocks 0..63 only): produce WT chunk [bid*64, bid*64+64) x 32
//   (fp16 transpose of W_e), then device-scope release atomicAdd(flag).
// Phase C (all blocks): independent preamble -- edge B-fragments, epilogue
//   multipliers, GRU step-1 for own row (overlaps producer latency) -- then
//   acquire-poll flag==64, then the MFMA i-loop + reduce + GRU step-2.
__global__ __launch_bounds__(256, 2)
void fused_kernel(const float* __restrict__ W_e,
                  const float* __restrict__ edges,
                  const float* __restrict__ nodes,
                  const float* __restrict__ mask,
                  const float* __restrict__ b_e,
                  const float* __restrict__ K,
                  const float* __restrict__ R,
                  const float* __restrict__ bias,
                  _Float16* __restrict__ WT,
                  int* __restrict__ flag,
                  float* __restrict__ out) {
    const int bid   = blockIdx.x;
    const int b     = bid >> 6;
    const int inode = bid & 63;
    const int tid   = threadIdx.x;
    const int w     = tid >> 6;
    const int lane  = tid & 63;
    const int quad  = lane >> 4;
    const int col   = lane & 15;
    const int row   = b * 64 + inode;

    __shared__ float S[4][64][17];            // 16 col-partials per (wave, i)
    __shared__ float P[4][64];
    __shared__ float xs[64], aggs[64], h1s[64];
    __shared__ float g1[192], g2[192];

    // ---- producer: blocks 0..63 write their WT chunk ----
    if (bid < 64) {
        const int d  = bid * 64 + (tid & 63);
        const int kq = tid >> 6;                       // k = kq*8 + j
        half8 buf;
#pragma unroll
        for (int j = 0; j < 8; ++j)
            buf[j] = (_Float16)W_e[(kq * 8 + j) * 4096 + d];   // coalesced over d
        *reinterpret_cast<half8*>(WT + d * 32 + kq * 8) = buf;
        __syncthreads();                               // drain block's stores to L2
        if (tid == 0)
            __hip_atomic_fetch_add(flag, 1, __ATOMIC_RELEASE, __HIP_MEMORY_SCOPE_AGENT);
    }

    // ---- consumer preamble (independent of WT) ----
    if (tid < 64) xs[tid] = nodes[row * 64 + tid];

    // B-operand fragments from fp32 edges, converted in-register (loop-invariant)
    half8 ef[4];
#pragma unroll
    for (int eb = 0; eb < 4; ++eb) {
        const float* ep = edges + (b * 4096 + inode * 64 + eb * 16 + col) * 32 + quad * 8;
        floatx4 e0 = *reinterpret_cast<const floatx4*>(ep);
        floatx4 e1 = *reinterpret_cast<const floatx4*>(ep + 4);
#pragma unroll
        for (int j = 0; j < 4; ++j) {
            ef[eb][j]     = (_Float16)e0[j];
            ef[eb][4 + j] = (_Float16)e1[j];
        }
    }

    // epilogue multipliers: xm[eb][rp] = {mask*nodes for r=2rp, 2rp+1}
    floatx2 xm[4][2];
#pragma unroll
    for (int eb = 0; eb < 4; ++eb) {
        int j = eb * 16 + col;
        float mk = mask[b * 4096 + inode * 64 + j];
#pragma unroll
        for (int r = 0; r < 4; ++r) {
            int jj = w * 16 + quad * 4 + r;
            xm[eb][r >> 1][r & 1] = mk * nodes[(b * 64 + j) * 64 + jj];
        }
    }

    // ---- GRU step 1 for own row (h_prev = 0), overlaps producer latency ----
    __syncthreads();
    if (tid < 192) {
        float acc = bias[tid];
#pragma unroll 8
        for (int k = 0; k < 64; ++k) acc = fmaf(xs[k], K[k * 192 + tid], acc);
        g1[tid] = acc;
    }
    __syncthreads();
    if (tid < 64) {
        float z  = sigmoidf_(g1[tid]       + bias[192 + tid]);
        float r  = sigmoidf_(g1[64 + tid]  + bias[256 + tid]);
        float hh = tanhf_  (g1[128 + tid] + r * bias[320 + tid]);
        h1s[tid] = (1.f - z) * hh;        // z*h_prev = 0
    }

    // ---- wait for all 64 WT chunks (device-scope acquire => L2 inv) ----
    if (tid == 0) {
        while (__hip_atomic_load(flag, __ATOMIC_ACQUIRE, __HIP_MEMORY_SCOPE_AGENT) < 64) {}
    }
    __syncthreads();

    // A-operand: WT rows d = i*64 + w*16 + col, k = quad*8 + j
    const _Float16* aptr = WT + (w * 16 + col) * 32 + quad * 8;
    const float*    bptr = b_e + w * 16 + quad * 4;

    // depth-2 software pipeline
    half8   af0 = *reinterpret_cast<const half8*>(aptr);
    floatx4 bf0 = *reinterpret_cast<const floatx4*>(bptr);
    half8   af1 = *reinterpret_cast<const half8*>(aptr + 2048);
    floatx4 bf1 = *reinterpret_cast<const floatx4*>(bptr + 64);

    for (int i = 0; i < 64; ++i) {
        int ip2 = (i + 2) & 63;   // wrap prefetch (reloads i=0,1 at end, harmless)
        half8   afn = *reinterpret_cast<const half8*>(aptr + ip2 * 2048);
        floatx4 bfn = *reinterpret_cast<const floatx4*>(bptr + ip2 * 64);

        floatx4 c[4];
        c[0] = __builtin_amdgcn_mfma_f32_16x16x32_f16(af0, ef[0], bf0, 0, 0, 0);
        c[1] = __builtin_amdgcn_mfma_f32_16x16x32_f16(af0, ef[1], bf0, 0, 0, 0);
        c[2] = __builtin_amdgcn_mfma_f32_16x16x32_f16(af0, ef[2], bf0, 0, 0, 0);
        c[3] = __builtin_amdgcn_mfma_f32_16x16x32_f16(af0, ef[3], bf0, 0, 0, 0);

        floatx2 sv = {0.f, 0.f};
#pragma unroll
        for (int eb = 0; eb < 4; ++eb) {
            floatx2* cp = reinterpret_cast<floatx2*>(&c[eb]);
            sv += relu2(cp[0]) * xm[eb][0];
            sv += relu2(cp[1]) * xm[eb][1];
        }
        float s = sv[0] + sv[1];
        s += __shfl_xor(s, 32);           // fold quads 0<->2, 1<->3
        s += __shfl_xor(s, 16);           // fold quads 0<->1
        if (lane < 16) S[w][i][lane] = s;

        af0 = af1; bf0 = bf1; af1 = afn; bf1 = bfn;
    }
    __syncthreads();

    {   // cross-lane partial sums: thread (ww = tid>>6, ii = tid&63) sums 16
        int ii = tid & 63, ww = tid >> 6;
        float p = 0.f;
#pragma unroll
        for (int l = 0; l < 16; ++l) p += S[ww][ii][l];
        P[ww][ii] = p;
    }
    __syncthreads();
    if (tid < 64) aggs[tid] = P[0][tid] + P[1][tid] + P[2][tid] + P[3][tid];
    __syncthreads();

    // ---- GRU step 2: out = gru(agg_row, h1) ----
    if (tid < 192) {
        float a1 = bias[tid], a2 = bias[192 + tid];
#pragma unroll 8
        for (int k = 0; k < 64; ++k) {
            a1 = fmaf(aggs[k], K[k * 192 + tid], a1);
            a2 = fmaf(h1s[k],  R[k * 192 + tid], a2);
        }
        g1[tid] = a1; g2[tid] = a2;
    }
    __syncthreads();
    if (tid < 64) {
        float z  = sigmoidf_(g1[tid]       + g2[tid]);
        float r  = sigmoidf_(g1[64 + tid]  + g2[64 + tid]);
        float hh = tanhf_  (g1[128 + tid] + r * g2[128 + tid]);
        out[row * 64 + tid] = z * h1s[tid] + (1.f - z) * hh;
    }
}

extern "C" void kernel_launch(void* const* d_in, const int* in_sizes, int n_in,
                              void* d_out, int out_size, void* d_ws, size_t ws_size,
                              hipStream_t stream) {
    const float* nodes = (const float*)d_in[0];
    const float* edges = (const float*)d_in[1];
    const float* mask  = (const float*)d_in[2];
    const float* W_e   = (const float*)d_in[3];
    const float* b_e   = (const float*)d_in[4];
    const float* gk    = (const float*)d_in[5];
    const float* gr    = (const float*)d_in[6];
    const float* gb    = (const float*)d_in[7];
    float* out = (float*)d_out;

    char* ws = (char*)d_ws;
    int*      flag = (int*)ws;                      // 4 B (poisoned 0xAA -> memset to 0)
    _Float16* WT   = (_Float16*)(ws + 256);         // 4096*32*2 = 256 KB

    hipMemsetAsync(flag, 0, sizeof(int), stream);   // capture-safe async memset
    fused_kernel<<<512, 256, 0, stream>>>(W_e, edges, nodes, mask, b_e,
                                          gk, gr, gb, WT, flag, out);
}

// Round 5
// 98.131 us; speedup vs baseline: 1.0378x; 1.0378x over previous
//
#include <hip/hip_runtime.h>

typedef _Float16 half8 __attribute__((ext_vector_type(8)));
typedef float floatx4 __attribute__((ext_vector_type(4)));
typedef float floatx2 __attribute__((ext_vector_type(2)));

#define BB 8
#define NN 64
#define DD 64
#define EE 32

__device__ __forceinline__ float sigmoidf_(float x) { return 1.f / (1.f + __expf(-x)); }
__device__ __forceinline__ float tanhf_(float x) {
    float e = __expf(2.f * x);
    return (e - 1.f) / (e + 1.f);
}
__device__ __forceinline__ floatx2 relu2(floatx2 v) {
    floatx2 z = {0.f, 0.f};
    return __builtin_elementwise_max(v, z);
}

// ---------------- prep: W transpose->fp16 AND GRU step 1 ----------------
// blocks [0,64):   WT[d][k] = (fp16)W_e[k][d]   (4096 x 32, A-operand friendly)
// blocks [64,192): h1[row][d] = gru(nodes_row, h=0)  (512 rows, 4 rows/block)
__global__ void prep_kernel(const float* __restrict__ W_e,
                            const float* __restrict__ nodes,
                            const float* __restrict__ K,
                            const float* __restrict__ bias,
                            _Float16* __restrict__ WT,
                            float* __restrict__ h1) {
    const int tid = threadIdx.x;
    if (blockIdx.x < 64) {
        const int d  = blockIdx.x * 64 + (tid & 63);
        const int kq = tid >> 6;                      // k = kq*8 + j
        half8 buf;
#pragma unroll
        for (int j = 0; j < 8; ++j)
            buf[j] = (_Float16)W_e[(kq * 8 + j) * 4096 + d];   // coalesced across d
        *reinterpret_cast<half8*>(WT + d * 32 + kq * 8) = buf;
    } else {
        const int blk = blockIdx.x - 64;              // 0..127
        const int rr  = tid >> 6;
        const int d   = tid & 63;
        const int row = blk * 4 + rr;                 // 0..511
        __shared__ float xs[4][64];
        xs[rr][d] = nodes[row * 64 + d];
        __syncthreads();
        float xz = bias[d], xr = bias[64 + d], xh = bias[128 + d];
#pragma unroll 8
        for (int k = 0; k < 64; ++k) {
            float xv = xs[rr][k];
            xz = fmaf(xv, K[k * 192 + d],       xz);
            xr = fmaf(xv, K[k * 192 + 64 + d],  xr);
            xh = fmaf(xv, K[k * 192 + 128 + d], xh);
        }
        float z  = sigmoidf_(xz + bias[192 + d]);
        float r  = sigmoidf_(xr + bias[256 + d]);
        float hh = tanhf_(xh + r * bias[320 + d]);
        h1[row * 64 + d] = (1.f - z) * hh;            // z*h_prev = 0
    }
}

// ---------------- fused: A-GEMM + relu + message + mask + j-sum + GRU step 2 ----------------
// One block per (b, i_node); 512 threads = 8 waves for 4 waves/SIMD latency hiding.
// Wave w: jj-block (w&3), i-half (w>>2) -> 32 i-iterations of 4 MFMAs each.
// Per i: C[d=i*64+jj, e] = b_e[d] + sum_k WT[d][k]*E[e][k]
// epilogue: s = sum relu(C)*mask[e]*nodes[j(e)][jj]; 2 shfl folds -> 16 partials -> LDS.
// Tail: cross-wave reduce -> agg row -> GRU step 2 (h1 from prep) -> out row.
__global__ __launch_bounds__(512, 4)
void fused_kernel(const _Float16* __restrict__ WT,
                  const float* __restrict__ edges,
                  const float* __restrict__ nodes,
                  const float* __restrict__ mask,
                  const float* __restrict__ b_e,
                  const float* __restrict__ K,
                  const float* __restrict__ R,
                  const float* __restrict__ bias,
                  const float* __restrict__ h1,
                  float* __restrict__ out) {
    const int b     = blockIdx.x >> 6;
    const int inode = blockIdx.x & 63;
    const int tid   = threadIdx.x;
    const int w     = tid >> 6;          // 0..7
    const int jw    = w & 3;             // jj-block
    const int ibase = (w >> 2) * 32;     // i-half
    const int lane  = tid & 63;
    const int quad  = lane >> 4;
    const int col   = lane & 15;
    const int row   = b * 64 + inode;

    __shared__ float S[64][4][17];       // [i][jj-block][16 col-partials] = 17.4 KB
    __shared__ float P[4][64];
    __shared__ float aggs[64], h1s[64];
    __shared__ float g1[192], g2[192];

    if (tid < 64) h1s[tid] = h1[row * 64 + tid];

    // B-operand fragments from fp32 edges, converted in-register (loop-invariant)
    half8 ef[4];
#pragma unroll
    for (int eb = 0; eb < 4; ++eb) {
        const float* ep = edges + (b * 4096 + inode * 64 + eb * 16 + col) * 32 + quad * 8;
        floatx4 e0 = *reinterpret_cast<const floatx4*>(ep);
        floatx4 e1 = *reinterpret_cast<const floatx4*>(ep + 4);
#pragma unroll
        for (int j = 0; j < 4; ++j) {
            ef[eb][j]     = (_Float16)e0[j];
            ef[eb][4 + j] = (_Float16)e1[j];
        }
    }

    // epilogue multipliers: xm[eb][rp] = {mask*nodes for r=2rp, 2rp+1}
    floatx2 xm[4][2];
#pragma unroll
    for (int eb = 0; eb < 4; ++eb) {
        int j = eb * 16 + col;
        float mk = mask[b * 4096 + inode * 64 + j];
#pragma unroll
        for (int r = 0; r < 4; ++r) {
            int jj = jw * 16 + quad * 4 + r;
            xm[eb][r >> 1][r & 1] = mk * nodes[(b * 64 + j) * 64 + jj];
        }
    }

    // A-operand: WT rows d = i*64 + jw*16 + col, k = quad*8 + j
    const _Float16* aptr = WT + (jw * 16 + col) * 32 + quad * 8;
    const float*    bptr = b_e + jw * 16 + quad * 4;

    // depth-2 software pipeline over this wave's 32 i's
    half8   af0 = *reinterpret_cast<const half8*>(aptr + ibase * 2048);
    floatx4 bf0 = *reinterpret_cast<const floatx4*>(bptr + ibase * 64);
    half8   af1 = *reinterpret_cast<const half8*>(aptr + (ibase + 1) * 2048);
    floatx4 bf1 = *reinterpret_cast<const floatx4*>(bptr + (ibase + 1) * 64);

    for (int ii = 0; ii < 32; ++ii) {
        int ip2 = ibase + ((ii + 2) & 31);   // wrap prefetch (harmless reload at end)
        half8   afn = *reinterpret_cast<const half8*>(aptr + ip2 * 2048);
        floatx4 bfn = *reinterpret_cast<const floatx4*>(bptr + ip2 * 64);

        floatx4 c[4];
        c[0] = __builtin_amdgcn_mfma_f32_16x16x32_f16(af0, ef[0], bf0, 0, 0, 0);
        c[1] = __builtin_amdgcn_mfma_f32_16x16x32_f16(af0, ef[1], bf0, 0, 0, 0);
        c[2] = __builtin_amdgcn_mfma_f32_16x16x32_f16(af0, ef[2], bf0, 0, 0, 0);
        c[3] = __builtin_amdgcn_mfma_f32_16x16x32_f16(af0, ef[3], bf0, 0, 0, 0);

        floatx2 sv = {0.f, 0.f};
#pragma unroll
        for (int eb = 0; eb < 4; ++eb) {
            floatx2* cp = reinterpret_cast<floatx2*>(&c[eb]);
            sv += relu2(cp[0]) * xm[eb][0];
            sv += relu2(cp[1]) * xm[eb][1];
        }
        float s = sv[0] + sv[1];
        s += __shfl_xor(s, 32);              // fold quads 0<->2, 1<->3
        s += __shfl_xor(s, 16);              // fold quads 0<->1
        if (lane < 16) S[ibase + ii][jw][lane] = s;

        af0 = af1; bf0 = bf1; af1 = afn; bf1 = bfn;
    }
    __syncthreads();

    if (tid < 256) {   // thread (ww = tid>>6, ii = tid&63) sums 16 col-partials
        int ii = tid & 63, ww = tid >> 6;
        float p = 0.f;
#pragma unroll
        for (int l = 0; l < 16; ++l) p += S[ii][ww][l];
        P[ww][ii] = p;
    }
    __syncthreads();
    if (tid < 64) aggs[tid] = P[0][tid] + P[1][tid] + P[2][tid] + P[3][tid];
    __syncthreads();

    // ---- GRU step 2: out = gru(agg_row, h1) ----
    if (tid < 192) {
        float a1 = bias[tid], a2 = bias[192 + tid];
#pragma unroll 8
        for (int k = 0; k < 64; ++k) {
            a1 = fmaf(aggs[k], K[k * 192 + tid], a1);
            a2 = fmaf(h1s[k],  R[k * 192 + tid], a2);
        }
        g1[tid] = a1; g2[tid] = a2;
    }
    __syncthreads();
    if (tid < 64) {
        float z  = sigmoidf_(g1[tid]       + g2[tid]);
        float r  = sigmoidf_(g1[64 + tid]  + g2[64 + tid]);
        float hh = tanhf_  (g1[128 + tid] + r * g2[128 + tid]);
        out[row * 64 + tid] = z * h1s[tid] + (1.f - z) * hh;
    }
}

extern "C" void kernel_launch(void* const* d_in, const int* in_sizes, int n_in,
                              void* d_out, int out_size, void* d_ws, size_t ws_size,
                              hipStream_t stream) {
    const float* nodes = (const float*)d_in[0];
    const float* edges = (const float*)d_in[1];
    const float* mask  = (const float*)d_in[2];
    const float* W_e   = (const float*)d_in[3];
    const float* b_e   = (const float*)d_in[4];
    const float* gk    = (const float*)d_in[5];
    const float* gr    = (const float*)d_in[6];
    const float* gb    = (const float*)d_in[7];
    float* out = (float*)d_out;

    char* ws = (char*)d_ws;
    _Float16* WT = (_Float16*)ws;              // 4096*32*2 = 256 KB
    float*    h1 = (float*)(ws + 262144);      // 512*64*4  = 128 KB

    prep_kernel<<<192, 256, 0, stream>>>(W_e, nodes, gk, gb, WT, h1);
    fused_kernel<<<512, 512, 0, stream>>>(WT, edges, nodes, mask, b_e, gk, gr, gb, h1, out);
}